// Round 10
// baseline (209.385 us; speedup 1.0000x reference)
//
#include <hip/hip_runtime.h>
#include <cstdint>
#include <cstddef>

// ---------------------------------------------------------------------------
// SparseMHADecoder: B=2, LQ=4096, LKV=2048, D=1024, H=16, d=64, span=16, stride=2
// R16: port gemm_out to the R15-verified quadrant-phased structure at 256x128
//      (32x8 = 256 blocks = exactly 1/CU, one round; was m97 128^2 x 512
//      blocks = 2 rounds). Staging: A-half = 2 gloads, B-half = 1 (6/K-tile).
//      Ledger re-derived: steady P1-wait vmcnt(4), P2-wait vmcnt(3), P4-wait
//      vmcnt(3) (fixpoint leaves Bhi+Ahi of t+1 = 3); tail VM2/VM0; prologue
//      no-op-safe. Half-alignment invariant identical to R15 (DS row = qrow
//      mod 8; DSA/DSB(h) touch only staging half h for every wave).
//      Same per-element k-order -> bit-identical output.
//      ONLY gemm_out changes; revert path = R15's m97 body.
// R15 carried: quadrant-phased 256x256 gemm_qkv (verified), half-strip wave
//      mapping, deadline staging Alo@P1/Blo@P2/Bhi@P3/Ahi@P4, counted vmcnt.
// R13 carried: vectorized ctx_gather. R12: prep_all hoisted convert,
//      workspace aliasing. R5/R6/R10: XOR swizzle, coalescing, XCD grouping.
// ---------------------------------------------------------------------------

typedef _Float16 f16;
typedef _Float16 f16x8 __attribute__((ext_vector_type(8)));
typedef float v4f __attribute__((ext_vector_type(4)));

#define B_  2
#define LQ_ 4096
#define LKV_ 2048
#define DMODEL 1024
#define NH 16
#define HD 64
#define SPAN 16
#define STRIDE 2

#define NQ_ELEMS  ((size_t)B_ * LQ_ * DMODEL)   // 8388608
#define NKV_ELEMS ((size_t)B_ * LKV_ * DMODEL)  // 4194304

#define BAR()   __builtin_amdgcn_s_barrier()
#define LGKM0() asm volatile("s_waitcnt lgkmcnt(0)" ::: "memory")
#define SB0()   __builtin_amdgcn_sched_barrier(0)
#define VM4()   asm volatile("s_waitcnt vmcnt(4)" ::: "memory")
#define VM3()   asm volatile("s_waitcnt vmcnt(3)" ::: "memory")
#define VM2()   asm volatile("s_waitcnt vmcnt(2)" ::: "memory")
#define VM0()   asm volatile("s_waitcnt vmcnt(0)" ::: "memory")

__device__ __forceinline__ void async_copy16(const f16* g, f16* l) {
    __builtin_amdgcn_global_load_lds((const __attribute__((address_space(1))) void*)g,
                                     (__attribute__((address_space(3))) void*)l, 16, 0, 0);
}

// ---- prep: 4 weight transposes (blocks 0..1023) + q/k/v f32->f16 convert ----
__global__ __launch_bounds__(256)
void prep_all(const float* __restrict__ W0, const float* __restrict__ W1,
              const float* __restrict__ W2, const float* __restrict__ W3,
              f16* __restrict__ T0, f16* __restrict__ T1,
              f16* __restrict__ T2, f16* __restrict__ T3,
              const float* __restrict__ q, const float* __restrict__ k,
              const float* __restrict__ v,
              f16* __restrict__ qh, f16* __restrict__ kh, f16* __restrict__ vh) {
    const int t = threadIdx.x;
    const int bid = blockIdx.x;
    if (bid < 1024) {                       // 16x16 tiles x 4 weights
        const int z = bid >> 8, rem = bid & 255;
        const int bx = rem & 15, byy = rem >> 4;
        const float* W;
        f16* Wt;
        switch (z) {
            case 0: W = W0; Wt = T0; break;
            case 1: W = W1; Wt = T1; break;
            case 2: W = W2; Wt = T2; break;
            default: W = W3; Wt = T3; break;
        }
        __shared__ float tile[64][65];
        const int r0 = byy * 64, c0 = bx * 64;
        const int tx = t & 63, ty = t >> 6; // (64,4)
        for (int i = ty; i < 64; i += 4)
            tile[i][tx] = W[(long)(r0 + i) * DMODEL + c0 + tx];
        __syncthreads();
        for (int i = ty; i < 64; i += 4)
            Wt[(long)(c0 + i) * DMODEL + r0 + tx] = (f16)tile[tx][i];
    } else {                                // streaming f32 -> f16 convert
        const int cid = bid - 1024;         // 0..8191
        const float* src;
        f16* dst;
        size_t base;
        if (cid < 4096)      { src = q; dst = qh; base = (size_t)cid * 2048; }
        else if (cid < 6144) { src = k; dst = kh; base = (size_t)(cid - 4096) * 2048; }
        else                 { src = v; dst = vh; base = (size_t)(cid - 6144) * 2048; }
        const size_t i = base + (size_t)t * 8;
        const float4 lo = *(const float4*)(src + i);
        const float4 hi = *(const float4*)(src + i + 4);
        f16x8 o = {(f16)lo.x, (f16)lo.y, (f16)lo.z, (f16)lo.w,
                   (f16)hi.x, (f16)hi.y, (f16)hi.z, (f16)hi.w};
        *(f16x8*)(dst + i) = o;
    }
}

// ---------------------------------------------------------------------------
// R15 quadrant-phased 256x256 GEMM body (f16 x f16 -> f16). VERIFIED.
// ---------------------------------------------------------------------------
__device__ __forceinline__ void gemm_qkv_body(const f16* __restrict__ Ah,
                                              const f16* __restrict__ Bt,
                                              f16* __restrict__ C,
                                              int rowTile, int colTile) {
    constexpr int K = DMODEL, N = DMODEL, NT = K / 64;
    __shared__ f16 lds[2 * 32768];          // 128 KB

    const int t = threadIdx.x;              // 512
    const int lane = t & 63, w = t >> 6;
    const int wm = w >> 2, wn = w & 3;      // 2M x 4N
    const int qrow = lane & 15, quad = lane >> 4;
    const long rowBase = (long)rowTile * 256;
    const long colBase = (long)colTile * 256;

    const int srow = t >> 3, sch = t & 7;
    const int gch = sch ^ (srow & 7);       // thread-constant
    const f16* aBase = Ah + (rowBase + srow) * (long)K + gch * 8;
    const f16* bBase = Bt + (colBase + srow) * (long)K + gch * 8;

    v4f acc[8][4] = {};
    f16x8 afr[4][2];                        // current A-half frags [m4][s]
    f16x8 bfr[4][2];                        // both B-halves kept  [bh*2+n2][s]

    auto STAGE = [&](int tt2, int op, int half) {   // 1 op-half = 2 gloads
        f16* dst = &lds[(tt2 & 1) * 32768 + op * 16384 + half * 8192 + t * 8];
        const f16* src = (op ? bBase : aBase) + (long)half * 128 * K + tt2 * 64;
        async_copy16(src, dst);
        async_copy16(src + 64 * (long)K, dst + 4096);
    };
    auto DSA = [&](int tt2, int h) {        // 8 ds_read_b128, half h ONLY
        const f16* lp = &lds[(tt2 & 1) * 32768];
#pragma unroll
        for (int m4 = 0; m4 < 4; ++m4)
#pragma unroll
            for (int s = 0; s < 2; ++s)
                afr[m4][s] = *(const f16x8*)(lp +
                    (h * 128 + wm * 64 + m4 * 16 + qrow) * 64 +
                    (((s * 4 + quad) ^ (qrow & 7)) * 8));
    };
    auto DSB = [&](int tt2, int h) {        // 4 ds_read_b128, half h ONLY
        const f16* lp = &lds[(tt2 & 1) * 32768 + 16384];
#pragma unroll
        for (int n2 = 0; n2 < 2; ++n2)
#pragma unroll
            for (int s = 0; s < 2; ++s)
                bfr[h * 2 + n2][s] = *(const f16x8*)(lp +
                    (h * 128 + wn * 32 + n2 * 16 + qrow) * 64 +
                    (((s * 4 + quad) ^ (qrow & 7)) * 8));
    };
    auto MQ = [&](int ah, int bh) {         // 16 MFMA, one C-quadrant
        __builtin_amdgcn_s_setprio(1);
#pragma unroll
        for (int s = 0; s < 2; ++s)
#pragma unroll
            for (int m4 = 0; m4 < 4; ++m4)
#pragma unroll
                for (int n2 = 0; n2 < 2; ++n2)
                    acc[ah * 4 + m4][bh * 2 + n2] =
                        __builtin_amdgcn_mfma_f32_16x16x32_f16(
                            afr[m4][s], bfr[bh * 2 + n2][s],
                            acc[ah * 4 + m4][bh * 2 + n2], 0, 0, 0);
        __builtin_amdgcn_s_setprio(0);
    };

    STAGE(0, 0, 0); STAGE(0, 1, 0); STAGE(0, 1, 1); STAGE(0, 0, 1);
    VM0();
    BAR();

#pragma unroll 2
    for (int tt = 0; tt < NT; ++tt) {
        const bool st = (tt + 1 < NT);
        DSA(tt, 0); DSB(tt, 0);
        if (st) STAGE(tt + 1, 0, 0);
        BAR(); LGKM0(); SB0();
        MQ(0, 0);
        if (st) { VM4(); } else { VM2(); }
        BAR();
        DSB(tt, 1);
        if (st) STAGE(tt + 1, 1, 0);
        BAR(); LGKM0(); SB0();
        MQ(0, 1);
        if (st) { VM4(); } else { VM0(); }
        BAR();
        DSA(tt, 1);
        if (st) STAGE(tt + 1, 1, 1);
        BAR(); LGKM0(); SB0();
        MQ(1, 0);
        BAR();
        if (st) STAGE(tt + 1, 0, 1);
        MQ(1, 1);
        if (st) VM4();
        BAR();
    }

#pragma unroll
    for (int m = 0; m < 8; ++m)
#pragma unroll
        for (int n = 0; n < 4; ++n) {
            const int ah = m >> 2, m4 = m & 3;
            const int bh = n >> 1, n2 = n & 1;
            const long col = colBase + bh * 128 + wn * 32 + n2 * 16 + qrow;
#pragma unroll
            for (int r = 0; r < 4; ++r) {
                const long row = rowBase + ah * 128 + wm * 64 + m4 * 16 + quad * 4 + r;
                C[row * (long)N + col] = (f16)acc[m][n][r];
            }
        }
}

__global__ __launch_bounds__(512)
void gemm_qkv(const f16* __restrict__ qf, const f16* __restrict__ kf,
              const f16* __restrict__ vf, const f16* __restrict__ WqT,
              const f16* __restrict__ WkT, const f16* __restrict__ WvT,
              f16* __restrict__ Qh, f16* __restrict__ Kh, f16* __restrict__ Vh) {
    const int id = (blockIdx.x & 7) * 32 + (blockIdx.x >> 3);  // bijective, 256
    const f16* A; const f16* Bt; f16* C; int rt, ct;
    if (id < 128)      { A = qf; Bt = WqT; C = Qh; rt = id >> 2; ct = id & 3; }
    else if (id < 192) { const int g = id - 128; A = kf; Bt = WkT; C = Kh; rt = g >> 2; ct = g & 3; }
    else               { const int g = id - 192; A = vf; Bt = WvT; C = Vh; rt = g >> 2; ct = g & 3; }
    gemm_qkv_body(A, Bt, C, rt, ct);
}

// ---------------------------------------------------------------------------
// R16 quadrant-phased 256x128 GEMM body (f16 x f16 -> f32 out).
// Tile buffer: A 16384 f16 (rows 0..255) then B 8192 f16 (cols 0..127); 48 KB,
// double-buffered = 96 KB. Staging: A-half = 2 gloads (128 rows), B-half = 1
// (64 cols). Waves 4M x 2N; strips: A row = h*128 + wm*32 + m2*16 + qrow,
// B col = h*64 + wn*32 + n2*16 + qrow (all rows = qrow mod 8: swizzle ok;
// DSA/DSB(h) touch only staging half h for every wave).
// ---------------------------------------------------------------------------
__global__ __launch_bounds__(512)
void gemm_out(const f16* __restrict__ Ah, const f16* __restrict__ Bt,
              float* __restrict__ C) {
    constexpr int K = DMODEL, N = DMODEL, NT = K / 64;
    __shared__ f16 lds[2 * 24576];          // 96 KB

    const int id = (blockIdx.x & 7) * 32 + (blockIdx.x >> 3);  // bijective, 256
    const int rt = id >> 3, ct = id & 7;    // A-panel shared per XCD

    const int t = threadIdx.x;              // 512
    const int lane = t & 63, w = t >> 6;
    const int wm = w >> 1, wn = w & 1;      // 4M x 2N
    const int qrow = lane & 15, quad = lane >> 4;
    const long rowBase = (long)rt * 256;
    const long colBase = (long)ct * 128;

    const int srow = t >> 3, sch = t & 7;
    const int gch = sch ^ (srow & 7);
    const f16* aBase = Ah + (rowBase + srow) * (long)K + gch * 8;
    const f16* bBase = Bt + (colBase + srow) * (long)K + gch * 8;

    v4f acc[4][4] = {};
    f16x8 afr[2][2];                        // current A-half frags [m2][s]
    f16x8 bfr[4][2];                        // both B-halves kept  [bh*2+n2][s]

    auto STAGEA = [&](int tt2, int half) {  // 2 gloads (128 rows)
        f16* dst = &lds[(tt2 & 1) * 24576 + half * 8192 + t * 8];
        const f16* src = aBase + (long)half * 128 * K + tt2 * 64;
        async_copy16(src, dst);
        async_copy16(src + 64 * (long)K, dst + 4096);
    };
    auto STAGEB = [&](int tt2, int half) {  // 1 gload (64 cols)
        f16* dst = &lds[(tt2 & 1) * 24576 + 16384 + half * 4096 + t * 8];
        const f16* src = bBase + (long)half * 64 * K + tt2 * 64;
        async_copy16(src, dst);
    };
    auto DSA = [&](int tt2, int h) {        // 4 ds_read_b128, half h ONLY
        const f16* lp = &lds[(tt2 & 1) * 24576];
#pragma unroll
        for (int m2 = 0; m2 < 2; ++m2)
#pragma unroll
            for (int s = 0; s < 2; ++s)
                afr[m2][s] = *(const f16x8*)(lp +
                    (h * 128 + wm * 32 + m2 * 16 + qrow) * 64 +
                    (((s * 4 + quad) ^ (qrow & 7)) * 8));
    };
    auto DSB = [&](int tt2, int h) {        // 4 ds_read_b128, half h ONLY
        const f16* lp = &lds[(tt2 & 1) * 24576 + 16384];
#pragma unroll
        for (int n2 = 0; n2 < 2; ++n2)
#pragma unroll
            for (int s = 0; s < 2; ++s)
                bfr[h * 2 + n2][s] = *(const f16x8*)(lp +
                    (h * 64 + wn * 32 + n2 * 16 + qrow) * 64 +
                    (((s * 4 + quad) ^ (qrow & 7)) * 8));
    };
    auto MQ = [&](int ah, int bh) {         // 8 MFMA, one C-quadrant
        __builtin_amdgcn_s_setprio(1);
#pragma unroll
        for (int s = 0; s < 2; ++s)
#pragma unroll
            for (int m2 = 0; m2 < 2; ++m2)
#pragma unroll
                for (int n2 = 0; n2 < 2; ++n2)
                    acc[ah * 2 + m2][bh * 2 + n2] =
                        __builtin_amdgcn_mfma_f32_16x16x32_f16(
                            afr[m2][s], bfr[bh * 2 + n2][s],
                            acc[ah * 2 + m2][bh * 2 + n2], 0, 0, 0);
        __builtin_amdgcn_s_setprio(0);
    };

    // prologue: tile0 fully staged (6 loads)
    STAGEA(0, 0); STAGEB(0, 0); STAGEB(0, 1); STAGEA(0, 1);
    VM0();
    BAR();

    // ledger (A-half=2, B-half=1): steady P1 vmcnt(4), P2 vmcnt(3),
    // P4 vmcnt(3); tail VM2/VM0; prologue iters are no-op-safe.
#pragma unroll 2
    for (int tt = 0; tt < NT; ++tt) {
        const bool st = (tt + 1 < NT);
        // P1: reads A half0 + B half0 of t; stages Alo(t+1) [2]
        DSA(tt, 0); DSB(tt, 0);
        if (st) STAGEA(tt + 1, 0);
        BAR(); LGKM0(); SB0();
        MQ(0, 0);
        if (st) { VM4(); } else { VM2(); }   // retire Bhi(t)
        BAR();
        // P2: reads B half1 of t; stages Blo(t+1) [1]
        DSB(tt, 1);
        if (st) STAGEB(tt + 1, 0);
        BAR(); LGKM0(); SB0();
        MQ(0, 1);
        if (st) { VM3(); } else { VM0(); }   // retire Ahi(t)
        BAR();
        // P3: reads A half1 of t; stages Bhi(t+1) [1]
        DSA(tt, 1);
        if (st) STAGEB(tt + 1, 1);
        BAR(); LGKM0(); SB0();
        MQ(1, 0);
        BAR();
        // P4: all frags in regs; stages Ahi(t+1) [2]
        if (st) STAGEA(tt + 1, 1);
        MQ(1, 1);
        if (st) VM3();                       // retire Alo+Blo(t+1)
        BAR();
    }

    // epilogue (f32 out); mapping matches DSA/DSB strips
#pragma unroll
    for (int m = 0; m < 4; ++m)
#pragma unroll
        for (int n = 0; n < 4; ++n) {
            const int ah = m >> 1, m2 = m & 1;
            const int bh = n >> 1, n2 = n & 1;
            const long col = colBase + bh * 64 + wn * 32 + n2 * 16 + qrow;
#pragma unroll
            for (int r = 0; r < 4; ++r) {
                const long row = rowBase + ah * 128 + wm * 32 + m2 * 16 + quad * 4 + r;
                C[row * (long)N + col] = acc[m][n][r];
            }
        }
}

// -------- per-column scores + softmax over the 16 valid query rows ----------
__global__ __launch_bounds__(256)
void attn_scores(const f16* __restrict__ Q, const f16* __restrict__ Km,
                 float* __restrict__ attnw) {
    const int c0 = blockIdx.x * 4, b = blockIdx.y;
    const int t = threadIdx.x;
    __shared__ f16 Qs[24 * 1032];   // rows 0..21 used; 49.5 KB
    __shared__ f16 Ks[4 * 1032];    // 8.25 KB

#pragma unroll
    for (int it = 0; it < 12; ++it) {
        const int ch = t + 256 * it;        // 24 rows x 128 chunks
        const int row = ch >> 7, off = (ch & 127) * 8;
        int qq = 2 * c0 + row;
        if (qq > LQ_ - 1) qq = LQ_ - 1;     // clamp staging; masked in score
        f16x8 x = *(const f16x8*)(Q + (size_t)(b * LQ_ + qq) * DMODEL + off);
        const int h = off >> 6, bb = (off >> 3) & 7;
        *(f16x8*)(&Qs[row * 1032 + h * 64 + ((bb + h) & 7) * 8]) = x;
    }
#pragma unroll
    for (int it = 0; it < 2; ++it) {
        const int ch = t + 256 * it;        // 4 rows x 128 chunks
        const int row = ch >> 7, off = (ch & 127) * 8;
        f16x8 x = *(const f16x8*)(Km + (size_t)(b * LKV_ + c0 + row) * DMODEL + off);
        const int h = off >> 6, bb = (off >> 3) & 7;
        *(f16x8*)(&Ks[row * 1032 + h * 64 + ((bb + h) & 7) * 8]) = x;
    }
    __syncthreads();

    const int h = t >> 4, j = t & 15;
#pragma unroll
    for (int ci = 0; ci < 4; ++ci) {
        const int c = c0 + ci;
        const int q = STRIDE * c + j;
        const int row = 2 * ci + j;
        float a = 0.f;
#pragma unroll
        for (int bb = 0; bb < 8; ++bb) {
            const int off = h * 64 + ((bb + h) & 7) * 8;
            f16x8 qv = *(const f16x8*)(&Qs[row * 1032 + off]);
            f16x8 kv = *(const f16x8*)(&Ks[ci * 1032 + off]);  // wave-broadcast
#pragma unroll
            for (int u = 0; u < 8; ++u) a += (float)qv[u] * (float)kv[u];
        }
        float s = (q < LQ_) ? a : -1e30f;
        float m = s;
#pragma unroll
        for (int o = 1; o < 16; o <<= 1) m = fmaxf(m, __shfl_xor(m, o, 64));
        float p = (q < LQ_) ? __expf(s - m) : 0.f;
        float sum = p;
#pragma unroll
        for (int o = 1; o < 16; o <<= 1) sum += __shfl_xor(sum, o, 64);
        attnw[(size_t)((b * LKV_ + c) * NH + h) * SPAN + j] = p / sum;
    }
}

// ---- ctx[b,q,h,:] = sum_i attn[b, q/2-i, h, (q&1)+2i] * V[b, q/2-i, h, :] ----
__global__ __launch_bounds__(256)
void ctx_gather(const float* __restrict__ attnw, const f16* __restrict__ V,
                f16* __restrict__ ctx) {
    const int q0 = blockIdx.x * 16, b = blockIdx.y;
    const int t = threadIdx.x;
    const int kbase = (q0 >> 1) - 7;
    __shared__ f16 Vs[16 * 1024];     // 32 KB
    __shared__ float A_lds[16 * 256]; // 16 KB

#pragma unroll
    for (int it = 0; it < 8; ++it) {
        const int ch = t + 256 * it;       // 16 rows x 128 chunks
        const int row = ch >> 7, off = (ch & 127) * 8;
        int k = kbase + row;
        k = (k < 0) ? 0 : ((k > LKV_ - 1) ? LKV_ - 1 : k);
        *(f16x8*)(&Vs[row * 1024 + off]) =
            *(const f16x8*)(V + (size_t)(b * LKV_ + k) * DMODEL + off);
    }
#pragma unroll
    for (int it = 0; it < 4; ++it) {
        const int ch = t + 256 * it;       // 16 rows x 64 chunks of 4 f32
        const int row = ch >> 6, off = (ch & 63) * 4;
        int k = kbase + row;
        k = (k < 0) ? 0 : ((k > LKV_ - 1) ? LKV_ - 1 : k);
        *(float4*)(&A_lds[row * 256 + off]) =
            *(const float4*)(attnw + (size_t)(b * LKV_ + k) * 256 + off);
    }
    __syncthreads();

    const int chunk = t & 127;            // (h, d8)
    const int h = chunk >> 3;             // 0..15
    const int d8 = (chunk & 7) * 8;       // 0..56
    const int qh = t >> 7;                // q parity slot (q0 even)
    const int aoff = h * 16 + qh;
    const int kq0 = q0 >> 1;

#pragma unroll
    for (int qp = 0; qp < 8; ++qp) {
        const int q = q0 + qp * 2 + qh;
        float acc[8] = {0.f, 0.f, 0.f, 0.f, 0.f, 0.f, 0.f, 0.f};
#pragma unroll
        for (int i = 0; i < 8; ++i) {
            if (kq0 + qp - i < 0) break;      // kq < 0 (first block only)
            const int rr = 7 + qp - i;        // kq - kbase, in [0,14]
            const float wgt = A_lds[rr * 256 + aoff + 2 * i];
            const f16x8 v8 = *(const f16x8*)(&Vs[rr * 1024 + h * 64 + d8]);
#pragma unroll
            for (int u = 0; u < 8; ++u) acc[u] += wgt * (float)v8[u];
        }
        f16x8 o = {(f16)acc[0], (f16)acc[1], (f16)acc[2], (f16)acc[3],
                   (f16)acc[4], (f16)acc[5], (f16)acc[6], (f16)acc[7]};
        *(f16x8*)(ctx + (size_t)(b * LQ_ + q) * DMODEL + h * HD + d8) = o;
    }
}

// ---------------------------------------------------------------------------
extern "C" void kernel_launch(void* const* d_in, const int* in_sizes, int n_in,
                              void* d_out, int out_size, void* d_ws, size_t ws_size,
                              hipStream_t stream) {
    const float* q  = (const float*)d_in[0];
    const float* k  = (const float*)d_in[1];
    const float* v  = (const float*)d_in[2];
    const float* Wq = (const float*)d_in[3];
    const float* Wk = (const float*)d_in[4];
    const float* Wv = (const float*)d_in[5];
    const float* Wo = (const float*)d_in[6];
    float* out = (float*)d_out;

    const size_t NW = (size_t)DMODEL * DMODEL;

    char* p = (char*)d_ws;
    f16* WqT = (f16*)p; p += NW * 2;                    // 2 MB
    f16* WkT = (f16*)p; p += NW * 2;
    f16* WvT = (f16*)p; p += NW * 2;
    f16* WoT = (f16*)p; p += NW * 2;
    f16* Qh  = (f16*)p; p += NQ_ELEMS * 2;              // 16 MB
    f16* Kh  = (f16*)p; p += NKV_ELEMS * 2;             // 8 MB
    f16* Vh  = (f16*)p; p += NKV_ELEMS * 2;             // 8 MB
    f16* qf  = (f16*)p; p += NQ_ELEMS * 2;              // 16 MB (dead after qkv)
    f16* kf  = (f16*)p; p += NKV_ELEMS * 2;             // 8 MB  (dead after qkv)
    f16* vf  = (f16*)p; p += NKV_ELEMS * 2;             // 8 MB  (dead after qkv)
    f16* ctxh = qf;                                     // alias (lifetime ok)
    float* attnw = (float*)kf;                          // alias (lifetime ok)

    // 1) weight transposes + q/k/v f32->f16 convert (one fused launch)
    prep_all<<<dim3(9216), 256, 0, stream>>>(Wq, Wk, Wv, Wo, WqT, WkT, WvT, WoT,
                                             q, k, v, qf, kf, vf);

    // 2) Q/K/V projections, quadrant-phased 256x256, 1 block/CU
    gemm_qkv<<<dim3(256), 512, 0, stream>>>(qf, kf, vf, WqT, WkT, WvT,
                                            Qh, Kh, Vh);

    // 3) per-column masked scores + query-axis softmax
    attn_scores<<<dim3(LKV_ / 4, B_), 256, 0, stream>>>(Qh, Kh, attnw);

    // 4) per-query gather of weighted V (vectorized)
    ctx_gather<<<dim3(LQ_ / 16, B_), 256, 0, stream>>>(attnw, Vh, ctxh);

    // 5) output projection, quadrant-phased 256x128, 1 block/CU
    gemm_out<<<dim3(256), 512, 0, stream>>>(ctxh, WoT, out);
}